// Round 1
// baseline (405.430 us; speedup 1.0000x reference)
//
#include <hip/hip_runtime.h>
#include <hip/hip_bf16.h>

#define LN_EPS 1e-5f

// -------- Kernel 1: scatter-add edges into agg + degree count --------
// Thread layout: idx = e*64 + d. One wave (64 lanes) == one edge row.
// Coalesced 256B read from x[src*64..], 64 contiguous atomicAdds to agg[dst*64..].
__global__ __launch_bounds__(256) void scatter_kernel(
    const float* __restrict__ x,
    const int*   __restrict__ ei,   // [2*E], src = ei[0..E), dst = ei[E..2E)
    float* __restrict__ agg,        // [N*64]
    float* __restrict__ cnt,        // [N]
    int E)
{
    long long idx   = (long long)blockIdx.x * blockDim.x + threadIdx.x;
    long long total = (long long)E * 64;
    if (idx >= total) return;
    int e = (int)(idx >> 6);
    int d = (int)(idx & 63);
    int src = ei[e];
    int dst = ei[E + e];
    atomicAdd(&agg[(long long)dst * 64 + d], x[(long long)src * 64 + d]);
    if (d == 0) atomicAdd(&cnt[dst], 1.0f);
}

// -------- Kernel 2: per-node mean, dual 64x64 matmul, LayerNorm, ELU --------
// Block = 256 threads = 4 waves, one node per wave; lane = output channel j.
__global__ __launch_bounds__(256) void node_kernel(
    const float* __restrict__ x,
    const float* __restrict__ agg,
    const float* __restrict__ cnt,
    const float* __restrict__ Wl,     // [64][64] row-major: Wl[j][d]
    const float* __restrict__ Wr,
    const float* __restrict__ bias,
    const float* __restrict__ gamma,
    const float* __restrict__ beta,
    float* __restrict__ out,
    int N)
{
    __shared__ float sWl[64][65];   // +1 pad: lane j reads row j -> 2-way bank alias (free)
    __shared__ float sWr[64][65];
    __shared__ float srow[4][130];  // [wave][ mean(0..63) | pad | x(65..128) ]

    int tid  = threadIdx.x;
    int wid  = tid >> 6;    // wave (node slot) 0..3
    int lane = tid & 63;    // output channel

    // Stage weights: 4096 floats each, 16 per thread, coalesced.
    for (int i = tid; i < 64 * 64; i += 256) {
        sWl[i >> 6][i & 63] = Wl[i];
        sWr[i >> 6][i & 63] = Wr[i];
    }
    __syncthreads();

    int node = blockIdx.x * 4 + wid;
    if (node >= N) return;

    // Lane d loads mean[d] and x[d] for this node.
    float c   = cnt[node];
    float inv = 1.0f / fmaxf(c, 1.0f);
    srow[wid][lane]      = agg[(long long)node * 64 + lane] * inv;
    srow[wid][65 + lane] = x[(long long)node * 64 + lane];
    // same-wave LDS write->read; compiler inserts lgkmcnt wait

    float acc = bias[lane];
    #pragma unroll
    for (int d = 0; d < 64; ++d) {
        // srow reads are same-address broadcast (free); sW reads are 2-way alias (free)
        acc += srow[wid][d] * sWl[lane][d] + srow[wid][65 + d] * sWr[lane][d];
    }

    // LayerNorm over the 64 lanes of this wave
    float s = acc, s2 = acc * acc;
    #pragma unroll
    for (int off = 32; off >= 1; off >>= 1) {
        s  += __shfl_xor(s,  off);
        s2 += __shfl_xor(s2, off);
    }
    float mu  = s * (1.0f / 64.0f);
    float var = s2 * (1.0f / 64.0f) - mu * mu;
    float hn  = (acc - mu) * rsqrtf(var + LN_EPS) * gamma[lane] + beta[lane];

    out[(long long)node * 64 + lane] = hn > 0.0f ? hn : expm1f(hn);
}

extern "C" void kernel_launch(void* const* d_in, const int* in_sizes, int n_in,
                              void* d_out, int out_size, void* d_ws, size_t ws_size,
                              hipStream_t stream) {
    const float* x     = (const float*)d_in[0];
    const int*   ei    = (const int*)  d_in[1];
    const float* Wl    = (const float*)d_in[2];
    const float* Wr    = (const float*)d_in[3];
    const float* bias  = (const float*)d_in[4];
    const float* gamma = (const float*)d_in[5];
    const float* beta  = (const float*)d_in[6];

    int N = in_sizes[0] / 64;
    int E = in_sizes[1] / 2;

    float* agg = (float*)d_ws;              // N*64 floats
    float* cnt = agg + (size_t)N * 64;      // N floats

    hipMemsetAsync(d_ws, 0, ((size_t)N * 64 + N) * sizeof(float), stream);

    long long total = (long long)E * 64;
    int sblocks = (int)((total + 255) / 256);
    scatter_kernel<<<sblocks, 256, 0, stream>>>(x, ei, agg, cnt, E);

    int nblocks = (N + 3) / 4;
    node_kernel<<<nblocks, 256, 0, stream>>>(x, agg, cnt, Wl, Wr, bias, gamma, beta,
                                             (float*)d_out, N);
}